// Round 2
// baseline (1310.588 us; speedup 1.0000x reference)
//
#include <hip/hip_runtime.h>
#include <hip/hip_bf16.h>
#include <cstdint>

// ---------------------------------------------------------------------------
// Attention block, bf16 MFMA pipeline:
//   cast -> fused QKV GEMM -> RoPE -> V transpose -> flash attention -> O GEMM
// Shapes: B=2 T=2048 DIM=4096 H=32 KVH=8 D=128, no mask, start_pos=0.
// NOTE: reference uses jnp.tile on the KV-head axis -> Q-head h attends
// KV-head (h % 8), NOT (h / 4). (Round-1 bug.)
// ---------------------------------------------------------------------------

typedef short bf16x8 __attribute__((ext_vector_type(8)));   // 8 bf16 = 4 VGPRs
typedef float f32x4  __attribute__((ext_vector_type(4)));

__device__ __forceinline__ float b2f(unsigned short h) {
  union { uint32_t u; float f; } v; v.u = ((uint32_t)h) << 16; return v.f;
}
__device__ __forceinline__ unsigned short f2b(float f) {
  union { float f; uint32_t u; } v; v.f = f;
  uint32_t r = (v.u + 0x7FFFu + ((v.u >> 16) & 1u)) >> 16;
  return (unsigned short)r;
}

#define GLDS16(gp, lp)                                                        \
  __builtin_amdgcn_global_load_lds(                                           \
      (const __attribute__((address_space(1))) unsigned int*)(gp),            \
      (__attribute__((address_space(3))) unsigned int*)(lp), 16, 0, 0)

// ---------------------------------------------------------------------------
// fp32 -> bf16 cast, 4 elements/thread
// ---------------------------------------------------------------------------
__global__ __launch_bounds__(256) void cast_f32_bf16(
    const float* __restrict__ in, unsigned short* __restrict__ out, int n4) {
  int i = blockIdx.x * 256 + threadIdx.x;
  if (i < n4) {
    float4 v = ((const float4*)in)[i];
    ushort4 o;
    o.x = f2b(v.x); o.y = f2b(v.y); o.z = f2b(v.z); o.w = f2b(v.w);
    ((ushort4*)out)[i] = o;
  }
}

// ---------------------------------------------------------------------------
// GEMM  C[m,n] = sum_k A[m,k]*B[n,k]   (A: MxK row-major, B: NxK row-major)
// 128x128 tile, BK=64, 4 waves each computing a 64x64 quadrant (4x4 MFMA 16x16x32).
// LDS chunked layout [kc][row][8] so ds_read_b128 frag loads are 2-way aliased only
// and global_load_lds (wave-uniform base + lane*16) lands chunks contiguously.
// ---------------------------------------------------------------------------
__device__ __forceinline__ void stout(float* p, float v) { *p = v; }
__device__ __forceinline__ void stout(unsigned short* p, float v) { *p = f2b(v); }

template <typename OUT>
__global__ __launch_bounds__(256, 2) void gemm_bt(
    const unsigned short* __restrict__ A, const unsigned short* __restrict__ B,
    OUT* __restrict__ C, int M, int N, int K) {
  __shared__ __align__(16) unsigned short As[8][128][8];  // 16 KB
  __shared__ __align__(16) unsigned short Bs[8][128][8];  // 16 KB

  const int tid  = threadIdx.x;
  const int lane = tid & 63;
  const int wave = tid >> 6;
  const int col  = lane & 15;
  const int quad = lane >> 4;
  const int bm = blockIdx.y * 128;
  const int bn = blockIdx.x * 128;
  const int wm = (wave & 1) * 64;
  const int wn = (wave >> 1) * 64;

  f32x4 acc[4][4];
#pragma unroll
  for (int i = 0; i < 4; ++i)
#pragma unroll
    for (int j = 0; j < 4; ++j) acc[i][j] = (f32x4){0.f, 0.f, 0.f, 0.f};

  // staging: chunk c = r*256 + tid ; row = c&127 ; kc = c>>7 = (tid>>7)+2r
  const int srow = tid & 127;
  const int skc  = tid >> 7;  // 0..1
  const unsigned short* Ag = A + (size_t)(bm + srow) * K + skc * 8;
  const unsigned short* Bg = B + (size_t)(bn + srow) * K + skc * 8;
  unsigned short* Al = &As[skc][srow][0];
  unsigned short* Bl = &Bs[skc][srow][0];

  for (int k0 = 0; k0 < K; k0 += 64) {
    __syncthreads();
#pragma unroll
    for (int r = 0; r < 4; ++r) {
      GLDS16(Ag + k0 + r * 16, Al + r * 2048);
      GLDS16(Bg + k0 + r * 16, Bl + r * 2048);
    }
    __syncthreads();
#pragma unroll
    for (int ks = 0; ks < 2; ++ks) {
      bf16x8 a[4], b[4];
#pragma unroll
      for (int i = 0; i < 4; ++i)
        a[i] = *(const bf16x8*)&As[ks * 4 + quad][wm + i * 16 + col][0];
#pragma unroll
      for (int j = 0; j < 4; ++j)
        b[j] = *(const bf16x8*)&Bs[ks * 4 + quad][wn + j * 16 + col][0];
#pragma unroll
      for (int i = 0; i < 4; ++i)
#pragma unroll
        for (int j = 0; j < 4; ++j)
          acc[i][j] = __builtin_amdgcn_mfma_f32_16x16x32_bf16(a[i], b[j],
                                                              acc[i][j], 0, 0, 0);
    }
  }

  // epilogue: D[row=quad*4+r][col=lane&15] per 16x16 tile
#pragma unroll
  for (int i = 0; i < 4; ++i) {
    int row = bm + wm + i * 16 + quad * 4;
#pragma unroll
    for (int j = 0; j < 4; ++j) {
      int cc = bn + wn + j * 16 + col;
#pragma unroll
      for (int r2 = 0; r2 < 4; ++r2)
        stout(C + (size_t)(row + r2) * N + cc, acc[i][j][r2]);
    }
  }
}

// ---------------------------------------------------------------------------
// RoPE in-place on qkv (4096 rows x 6144 cols): heads 0..31 = q, 32..39 = k.
// pair (2i,2i+1) of head col, angle tables indexed [t][i], t = row % 2048.
// ---------------------------------------------------------------------------
__global__ __launch_bounds__(256) void rope_qk(
    unsigned short* __restrict__ qkv, const float* __restrict__ cosT,
    const float* __restrict__ sinT) {
  int idx = blockIdx.x * 256 + threadIdx.x;  // < 4096*2560
  int m = idx / 2560;
  int p = idx - m * 2560;
  int head = p >> 6, i = p & 63;
  int t = m & 2047;
  unsigned short* ptr = qkv + (size_t)m * 6144 + head * 128 + i * 2;
  ushort2 xy = *(const ushort2*)ptr;
  float x = b2f(xy.x), y = b2f(xy.y);
  float c = cosT[t * 64 + i], s = sinT[t * 64 + i];
  ushort2 o;
  o.x = f2b(x * c - y * s);
  o.y = f2b(x * s + y * c);
  *(ushort2*)ptr = o;
}

// ---------------------------------------------------------------------------
// V transpose: vt[(b*8+kvh)*128 + d][s] = qkv[b*2048+s][5120 + kvh*128 + d]
// 64x64 LDS tiles.
// ---------------------------------------------------------------------------
__global__ __launch_bounds__(256) void transpose_v(
    const unsigned short* __restrict__ qkv, unsigned short* __restrict__ vt) {
  __shared__ unsigned short tile[64][72];
  int b = blockIdx.z >> 3, kvh = blockIdx.z & 7;
  int s0 = blockIdx.x * 64, d0 = blockIdx.y * 64;
  int tc = threadIdx.x & 63, tr = threadIdx.x >> 6;  // tr 0..3
#pragma unroll
  for (int r = 0; r < 16; ++r) {
    int row = r * 4 + tr;  // s within tile
    tile[row][tc] =
        qkv[(size_t)(b * 2048 + s0 + row) * 6144 + 5120 + kvh * 128 + d0 + tc];
  }
  __syncthreads();
#pragma unroll
  for (int r = 0; r < 16; ++r) {
    int drow = r * 4 + tr;  // d within tile
    vt[(size_t)((b * 8 + kvh) * 128 + d0 + drow) * 2048 + s0 + tc] =
        tile[tc][drow];
  }
}

// ---------------------------------------------------------------------------
// Flash attention. grid (qt=16, h=32, b=2), 256 threads (4 waves).
// Q-tile 128 rows (per-wave 32 rows, Q frags in registers), S-tile 64.
// Scores: Q(A-frag regs) x K-tile(LDS, B^T form). Online softmax per row,
// row stats reduced with quad-local shuffles (rows never cross waves).
// P -> LDS (A-layout), PV with Vt tile (B^T form) staged via global_load_lds.
// KV-head mapping: reference tiles the KV axis -> kvh = h % 8.
// ---------------------------------------------------------------------------
__global__ __launch_bounds__(256, 2) void attn(
    const unsigned short* __restrict__ qkv, const unsigned short* __restrict__ vt,
    unsigned short* __restrict__ ctx) {
  constexpr int T = 2048, LD = 6144;
  const int qt = blockIdx.x, h = blockIdx.y, b = blockIdx.z;
  const int kvh = h & 7;  // jnp.tile semantics: head h -> kv head h % 8
  const int tid = threadIdx.x, lane = tid & 63, wave = tid >> 6;
  const int col = lane & 15, quad = lane >> 4;

  __shared__ __align__(1024) char smem[49152];
  auto Qs = (unsigned short(*)[128][8])smem;          // [16][128][8] (phase 0)
  auto Ks = (unsigned short(*)[64][8])smem;           // [16][64][8]
  auto Vs = (unsigned short(*)[128][8])(smem + 16384);// [8][128][8]
  auto Ps = (unsigned short(*)[128][8])(smem + 32768);// [8][128][8]

  // ---- stage Q tile (128 x 128) ----
  {
    const int row = tid & 127, kc0 = tid >> 7;  // kc0 0..1
    const unsigned short* g =
        qkv + (size_t)(b * T + qt * 128 + row) * LD + h * 128 + kc0 * 8;
    unsigned short* l = &Qs[kc0][row][0];
#pragma unroll
    for (int r = 0; r < 8; ++r) GLDS16(g + r * 16, l + r * 2048);
  }
  __syncthreads();

  bf16x8 qf[2][4];
#pragma unroll
  for (int mi = 0; mi < 2; ++mi)
#pragma unroll
    for (int ks = 0; ks < 4; ++ks)
      qf[mi][ks] = *(const bf16x8*)&Qs[ks * 4 + quad][wave * 32 + mi * 16 + col][0];

  float mrow[2][4], lrow[2][4];
  f32x4 oacc[2][8];
#pragma unroll
  for (int mi = 0; mi < 2; ++mi)
#pragma unroll
    for (int r = 0; r < 4; ++r) { mrow[mi][r] = -1e30f; lrow[mi][r] = 0.f; }
#pragma unroll
  for (int mi = 0; mi < 2; ++mi)
#pragma unroll
    for (int d = 0; d < 8; ++d) oacc[mi][d] = (f32x4){0.f, 0.f, 0.f, 0.f};

  const float scale = 0.08838834764831845f;  // 1/sqrt(128)
  const float l2e = 1.4426950408889634f;

  for (int s0 = 0; s0 < T; s0 += 64) {
    __syncthreads();  // protect LDS (Q frags read / prev iter K,V,P reads done)
    // ---- stage K tile (64 s-rows x 128 d), chunk c=r*256+tid ----
    {
      const int srow = tid & 63, kc0 = tid >> 6;  // kc0 0..3
      const unsigned short* g =
          qkv + (size_t)(b * T + s0 + srow) * LD + 4096 + kvh * 128 + kc0 * 8;
      unsigned short* l = &Ks[kc0][srow][0];
#pragma unroll
      for (int r = 0; r < 4; ++r) GLDS16(g + r * 32, l + r * 2048);
      // ---- stage Vt tile (128 d-rows x 64 s-cols) ----
      const int drow = tid & 127, sc0 = tid >> 7;  // sc0 0..1
      const unsigned short* gv =
          vt + (size_t)((b * 8 + kvh) * 128 + drow) * T + s0 + sc0 * 8;
      unsigned short* lv = &Vs[sc0][drow][0];
#pragma unroll
      for (int r = 0; r < 4; ++r) GLDS16(gv + r * 16, lv + r * 2048);
    }
    __syncthreads();

    // ---- scores: S = Q @ K^T ----
    f32x4 sacc[2][4];
#pragma unroll
    for (int mi = 0; mi < 2; ++mi)
#pragma unroll
      for (int j = 0; j < 4; ++j) sacc[mi][j] = (f32x4){0.f, 0.f, 0.f, 0.f};
#pragma unroll
    for (int ks = 0; ks < 4; ++ks) {
      bf16x8 bk[4];
#pragma unroll
      for (int j = 0; j < 4; ++j)
        bk[j] = *(const bf16x8*)&Ks[ks * 4 + quad][j * 16 + col][0];
#pragma unroll
      for (int mi = 0; mi < 2; ++mi)
#pragma unroll
        for (int j = 0; j < 4; ++j)
          sacc[mi][j] = __builtin_amdgcn_mfma_f32_16x16x32_bf16(
              qf[mi][ks], bk[j], sacc[mi][j], 0, 0, 0);
    }

    // ---- online softmax (row = wave*32 + mi*16 + quad*4 + r) ----
#pragma unroll
    for (int mi = 0; mi < 2; ++mi) {
#pragma unroll
      for (int r = 0; r < 4; ++r) {
        float mx = sacc[mi][0][r];
#pragma unroll
        for (int j = 1; j < 4; ++j) mx = fmaxf(mx, sacc[mi][j][r]);
        mx = fmaxf(mx, __shfl_xor(mx, 1));
        mx = fmaxf(mx, __shfl_xor(mx, 2));
        mx = fmaxf(mx, __shfl_xor(mx, 4));
        mx = fmaxf(mx, __shfl_xor(mx, 8));
        mx *= scale;
        float mold = mrow[mi][r];
        float mnew = fmaxf(mold, mx);
        float alpha = exp2f((mold - mnew) * l2e);
        mrow[mi][r] = mnew;
        float rsum = 0.f;
#pragma unroll
        for (int j = 0; j < 4; ++j) {
          float pv = exp2f((sacc[mi][j][r] * scale - mnew) * l2e);
          sacc[mi][j][r] = pv;
          rsum += pv;
        }
        rsum += __shfl_xor(rsum, 1);
        rsum += __shfl_xor(rsum, 2);
        rsum += __shfl_xor(rsum, 4);
        rsum += __shfl_xor(rsum, 8);
        lrow[mi][r] = lrow[mi][r] * alpha + rsum;
#pragma unroll
        for (int d = 0; d < 8; ++d) oacc[mi][d][r] *= alpha;
        // write P (bf16) in A-layout chunks [sc][m][8]
        int prow = wave * 32 + mi * 16 + quad * 4 + r;
#pragma unroll
        for (int j = 0; j < 4; ++j) {
          int sc = (j * 16 + col) >> 3;
          Ps[sc][prow][col & 7] = f2b(sacc[mi][j][r]);
        }
      }
    }
    // (P rows are wave-private: same-wave DS ops are processed in order,
    //  so no barrier needed between P write and P read.)

    // ---- O += P @ V ----
#pragma unroll
    for (int ks = 0; ks < 2; ++ks) {
      bf16x8 ap[2];
#pragma unroll
      for (int mi = 0; mi < 2; ++mi)
        ap[mi] = *(const bf16x8*)&Ps[ks * 4 + quad][wave * 32 + mi * 16 + col][0];
#pragma unroll
      for (int di = 0; di < 8; ++di) {
        bf16x8 bv = *(const bf16x8*)&Vs[ks * 4 + quad][di * 16 + col][0];
#pragma unroll
        for (int mi = 0; mi < 2; ++mi)
          oacc[mi][di] = __builtin_amdgcn_mfma_f32_16x16x32_bf16(
              ap[mi], bv, oacc[mi][di], 0, 0, 0);
      }
    }
  }

  // ---- epilogue: ctx[b*T + t][h*128 + d] = O / l ----
#pragma unroll
  for (int mi = 0; mi < 2; ++mi) {
#pragma unroll
    for (int r = 0; r < 4; ++r) {
      float inv = 1.0f / lrow[mi][r];
      int row = qt * 128 + wave * 32 + mi * 16 + quad * 4 + r;
#pragma unroll
      for (int di = 0; di < 8; ++di)
        ctx[(size_t)(b * T + row) * 4096 + h * 128 + di * 16 + col] =
            f2b(oacc[mi][di][r] * inv);
    }
  }
}

// ---------------------------------------------------------------------------
// launch
// ---------------------------------------------------------------------------
extern "C" void kernel_launch(void* const* d_in, const int* in_sizes, int n_in,
                              void* d_out, int out_size, void* d_ws,
                              size_t ws_size, hipStream_t stream) {
  const float* x  = (const float*)d_in[0];
  const float* wq = (const float*)d_in[1];
  const float* wk = (const float*)d_in[2];
  const float* wv = (const float*)d_in[3];
  const float* wo = (const float*)d_in[4];
  const float* fc = (const float*)d_in[5];
  const float* fs = (const float*)d_in[6];
  float* out = (float*)d_out;

  char* ws = (char*)d_ws;
  // region A: xb (x bf16), later reused as ctx        : 32 MB
  // region B: wqkv bf16, later reused as wo bf16      : 48 MB
  // region C: qkv activations bf16                    : 48 MB
  // region D: v transposed bf16                       :  8 MB
  unsigned short* xb  = (unsigned short*)(ws);
  unsigned short* wb  = (unsigned short*)(ws + 33554432);
  unsigned short* qkv = (unsigned short*)(ws + 33554432 + 50331648);
  unsigned short* vtp = (unsigned short*)(ws + 33554432 + 50331648 + 50331648);

  cast_f32_bf16<<<16384, 256, 0, stream>>>(x, xb, 4194304);
  cast_f32_bf16<<<16384, 256, 0, stream>>>(wq, wb, 4194304);
  cast_f32_bf16<<<4096, 256, 0, stream>>>(wk, wb + 16777216, 1048576);
  cast_f32_bf16<<<4096, 256, 0, stream>>>(wv, wb + 20971520, 1048576);

  dim3 g1(48, 32);
  gemm_bt<unsigned short><<<g1, 256, 0, stream>>>(xb, wb, qkv, 4096, 6144, 4096);

  cast_f32_bf16<<<16384, 256, 0, stream>>>(wo, wb, 4194304);  // reuse region B

  rope_qk<<<40960, 256, 0, stream>>>(qkv, fc, fs);

  dim3 g2(32, 2, 16);
  transpose_v<<<g2, 256, 0, stream>>>(qkv, vtp);

  dim3 g3(16, 32, 2);
  attn<<<g3, 256, 0, stream>>>(qkv, vtp, xb);  // ctx -> region A

  dim3 g4(32, 32);
  gemm_bt<float><<<g4, 256, 0, stream>>>(xb, wb, out, 4096, 4096, 4096);
}

// Round 3
// 929.712 us; speedup vs baseline: 1.4097x; 1.4097x over previous
//
#include <hip/hip_runtime.h>
#include <hip/hip_bf16.h>
#include <cstdint>

// ---------------------------------------------------------------------------
// Attention block, bf16 MFMA pipeline:
//   cast -> fused QKV GEMM -> RoPE -> V transpose -> flash attention -> O GEMM
// Shapes: B=2 T=2048 DIM=4096 H=32 KVH=8 D=128, no mask, start_pos=0.
// KV mapping: jnp.tile -> Q-head h attends KV-head (h % 8).
// R3: GEMM staging rewritten for coalesced GLDS — 8 lanes per 128B row
// segment (16 full lines/instr, was 64 quarter-used lines), XOR-swizzled
// chunk placement keeps fragment ds_read_b128 conflict-free.
// ---------------------------------------------------------------------------

typedef short bf16x8 __attribute__((ext_vector_type(8)));   // 8 bf16 = 4 VGPRs
typedef float f32x4  __attribute__((ext_vector_type(4)));

__device__ __forceinline__ float b2f(unsigned short h) {
  union { uint32_t u; float f; } v; v.u = ((uint32_t)h) << 16; return v.f;
}
__device__ __forceinline__ unsigned short f2b(float f) {
  union { float f; uint32_t u; } v; v.f = f;
  uint32_t r = (v.u + 0x7FFFu + ((v.u >> 16) & 1u)) >> 16;
  return (unsigned short)r;
}

#define GLDS16(gp, lp)                                                        \
  __builtin_amdgcn_global_load_lds(                                           \
      (const __attribute__((address_space(1))) unsigned int*)(gp),            \
      (__attribute__((address_space(3))) unsigned int*)(lp), 16, 0, 0)

// ---------------------------------------------------------------------------
// fp32 -> bf16 cast, 4 elements/thread
// ---------------------------------------------------------------------------
__global__ __launch_bounds__(256) void cast_f32_bf16(
    const float* __restrict__ in, unsigned short* __restrict__ out, int n4) {
  int i = blockIdx.x * 256 + threadIdx.x;
  if (i < n4) {
    float4 v = ((const float4*)in)[i];
    ushort4 o;
    o.x = f2b(v.x); o.y = f2b(v.y); o.z = f2b(v.z); o.w = f2b(v.w);
    ((ushort4*)out)[i] = o;
  }
}

// ---------------------------------------------------------------------------
// GEMM  C[m,n] = sum_k A[m,k]*B[n,k]   (A: MxK row-major, B: NxK row-major)
// 128x128 tile, BK=64, 4 waves each computing a 64x64 quadrant.
// LDS: row-major [128][64] (128B rows). Staging: linear chunk c = r*256+tid,
// LDS dest = c*16B (lane-contiguous per wave), row = c>>3, slot = c&7,
// global chunk = slot ^ (row&7)  -> per instruction a wave reads 8 rows x
// 128B contiguous (16 fully-used cache lines). Fragment read slot =
// (ks*4+quad) ^ (col&7) -> uniform 8 words/bank (conflict-free).
// ---------------------------------------------------------------------------
__device__ __forceinline__ void stout(float* p, float v) { *p = v; }
__device__ __forceinline__ void stout(unsigned short* p, float v) { *p = f2b(v); }

template <typename OUT>
__global__ __launch_bounds__(256, 2) void gemm_bt(
    const unsigned short* __restrict__ A, const unsigned short* __restrict__ B,
    OUT* __restrict__ C, int M, int N, int K) {
  __shared__ __align__(16) unsigned short As[128][64];  // 16 KB
  __shared__ __align__(16) unsigned short Bs[128][64];  // 16 KB

  const int tid  = threadIdx.x;
  const int lane = tid & 63;
  const int wave = tid >> 6;
  const int col  = lane & 15;
  const int quad = lane >> 4;
  const int bm = blockIdx.y * 128;
  const int bn = blockIdx.x * 128;
  const int wm = (wave & 1) * 64;
  const int wn = (wave >> 1) * 64;

  f32x4 acc[4][4];
#pragma unroll
  for (int i = 0; i < 4; ++i)
#pragma unroll
    for (int j = 0; j < 4; ++j) acc[i][j] = (f32x4){0.f, 0.f, 0.f, 0.f};

  // staging: chunk c = r*256 + tid ; row = c>>3 = r*32 + (tid>>3) ; slot = tid&7
  // gchunk = slot ^ (row&7); row&7 == (tid>>3)&7 (r*32 ≡ 0 mod 8) -> r-invariant.
  const int srow0  = tid >> 3;                    // 0..31
  const int gchunk = (tid & 7) ^ ((tid >> 3) & 7);
  const unsigned short* Ag = A + (size_t)(bm + srow0) * K + gchunk * 8;
  const unsigned short* Bg = B + (size_t)(bn + srow0) * K + gchunk * 8;
  unsigned short* Al = &As[0][0] + tid * 8;       // + r*2048 elems (= 32 rows)
  unsigned short* Bl = &Bs[0][0] + tid * 8;

  for (int k0 = 0; k0 < K; k0 += 64) {
    __syncthreads();
#pragma unroll
    for (int r = 0; r < 4; ++r) {
      GLDS16(Ag + k0 + (size_t)r * 32 * K, Al + r * 2048);
      GLDS16(Bg + k0 + (size_t)r * 32 * K, Bl + r * 2048);
    }
    __syncthreads();
#pragma unroll
    for (int ks = 0; ks < 2; ++ks) {
      bf16x8 a[4], b[4];
      const int slot = ((ks * 4 + quad) ^ (col & 7)) * 8;
#pragma unroll
      for (int i = 0; i < 4; ++i)
        a[i] = *(const bf16x8*)&As[wm + i * 16 + col][slot];
#pragma unroll
      for (int j = 0; j < 4; ++j)
        b[j] = *(const bf16x8*)&Bs[wn + j * 16 + col][slot];
#pragma unroll
      for (int i = 0; i < 4; ++i)
#pragma unroll
        for (int j = 0; j < 4; ++j)
          acc[i][j] = __builtin_amdgcn_mfma_f32_16x16x32_bf16(a[i], b[j],
                                                              acc[i][j], 0, 0, 0);
    }
  }

  // epilogue: D[row=quad*4+r][col=lane&15] per 16x16 tile
#pragma unroll
  for (int i = 0; i < 4; ++i) {
    int row = bm + wm + i * 16 + quad * 4;
#pragma unroll
    for (int j = 0; j < 4; ++j) {
      int cc = bn + wn + j * 16 + col;
#pragma unroll
      for (int r2 = 0; r2 < 4; ++r2)
        stout(C + (size_t)(row + r2) * N + cc, acc[i][j][r2]);
    }
  }
}

// ---------------------------------------------------------------------------
// RoPE in-place on qkv (4096 rows x 6144 cols): heads 0..31 = q, 32..39 = k.
// ---------------------------------------------------------------------------
__global__ __launch_bounds__(256) void rope_qk(
    unsigned short* __restrict__ qkv, const float* __restrict__ cosT,
    const float* __restrict__ sinT) {
  int idx = blockIdx.x * 256 + threadIdx.x;  // < 4096*2560
  int m = idx / 2560;
  int p = idx - m * 2560;
  int head = p >> 6, i = p & 63;
  int t = m & 2047;
  unsigned short* ptr = qkv + (size_t)m * 6144 + head * 128 + i * 2;
  ushort2 xy = *(const ushort2*)ptr;
  float x = b2f(xy.x), y = b2f(xy.y);
  float c = cosT[t * 64 + i], s = sinT[t * 64 + i];
  ushort2 o;
  o.x = f2b(x * c - y * s);
  o.y = f2b(x * s + y * c);
  *(ushort2*)ptr = o;
}

// ---------------------------------------------------------------------------
// V transpose: vt[(b*8+kvh)*128 + d][s] = qkv[b*2048+s][5120 + kvh*128 + d]
// ---------------------------------------------------------------------------
__global__ __launch_bounds__(256) void transpose_v(
    const unsigned short* __restrict__ qkv, unsigned short* __restrict__ vt) {
  __shared__ unsigned short tile[64][72];
  int b = blockIdx.z >> 3, kvh = blockIdx.z & 7;
  int s0 = blockIdx.x * 64, d0 = blockIdx.y * 64;
  int tc = threadIdx.x & 63, tr = threadIdx.x >> 6;  // tr 0..3
#pragma unroll
  for (int r = 0; r < 16; ++r) {
    int row = r * 4 + tr;  // s within tile
    tile[row][tc] =
        qkv[(size_t)(b * 2048 + s0 + row) * 6144 + 5120 + kvh * 128 + d0 + tc];
  }
  __syncthreads();
#pragma unroll
  for (int r = 0; r < 16; ++r) {
    int drow = r * 4 + tr;  // d within tile
    vt[(size_t)((b * 8 + kvh) * 128 + d0 + drow) * 2048 + s0 + tc] =
        tile[tc][drow];
  }
}

// ---------------------------------------------------------------------------
// Flash attention. grid (qt=16, h=32, b=2), 256 threads (4 waves).
// (unchanged from round 2 — kvh = h & 7 per jnp.tile semantics)
// ---------------------------------------------------------------------------
__global__ __launch_bounds__(256, 2) void attn(
    const unsigned short* __restrict__ qkv, const unsigned short* __restrict__ vt,
    unsigned short* __restrict__ ctx) {
  constexpr int T = 2048, LD = 6144;
  const int qt = blockIdx.x, h = blockIdx.y, b = blockIdx.z;
  const int kvh = h & 7;  // jnp.tile semantics: head h -> kv head h % 8
  const int tid = threadIdx.x, lane = tid & 63, wave = tid >> 6;
  const int col = lane & 15, quad = lane >> 4;

  __shared__ __align__(1024) char smem[49152];
  auto Qs = (unsigned short(*)[128][8])smem;          // [16][128][8] (phase 0)
  auto Ks = (unsigned short(*)[64][8])smem;           // [16][64][8]
  auto Vs = (unsigned short(*)[128][8])(smem + 16384);// [8][128][8]
  auto Ps = (unsigned short(*)[128][8])(smem + 32768);// [8][128][8]

  // ---- stage Q tile (128 x 128) ----
  {
    const int row = tid & 127, kc0 = tid >> 7;  // kc0 0..1
    const unsigned short* g =
        qkv + (size_t)(b * T + qt * 128 + row) * LD + h * 128 + kc0 * 8;
    unsigned short* l = &Qs[kc0][row][0];
#pragma unroll
    for (int r = 0; r < 8; ++r) GLDS16(g + r * 16, l + r * 2048);
  }
  __syncthreads();

  bf16x8 qf[2][4];
#pragma unroll
  for (int mi = 0; mi < 2; ++mi)
#pragma unroll
    for (int ks = 0; ks < 4; ++ks)
      qf[mi][ks] = *(const bf16x8*)&Qs[ks * 4 + quad][wave * 32 + mi * 16 + col][0];

  float mrow[2][4], lrow[2][4];
  f32x4 oacc[2][8];
#pragma unroll
  for (int mi = 0; mi < 2; ++mi)
#pragma unroll
    for (int r = 0; r < 4; ++r) { mrow[mi][r] = -1e30f; lrow[mi][r] = 0.f; }
#pragma unroll
  for (int mi = 0; mi < 2; ++mi)
#pragma unroll
    for (int d = 0; d < 8; ++d) oacc[mi][d] = (f32x4){0.f, 0.f, 0.f, 0.f};

  const float scale = 0.08838834764831845f;  // 1/sqrt(128)
  const float l2e = 1.4426950408889634f;

  for (int s0 = 0; s0 < T; s0 += 64) {
    __syncthreads();
    // ---- stage K tile (64 s-rows x 128 d) ----
    {
      const int srow = tid & 63, kc0 = tid >> 6;  // kc0 0..3
      const unsigned short* g =
          qkv + (size_t)(b * T + s0 + srow) * LD + 4096 + kvh * 128 + kc0 * 8;
      unsigned short* l = &Ks[kc0][srow][0];
#pragma unroll
      for (int r = 0; r < 4; ++r) GLDS16(g + r * 32, l + r * 2048);
      // ---- stage Vt tile (128 d-rows x 64 s-cols) ----
      const int drow = tid & 127, sc0 = tid >> 7;  // sc0 0..1
      const unsigned short* gv =
          vt + (size_t)((b * 8 + kvh) * 128 + drow) * T + s0 + sc0 * 8;
      unsigned short* lv = &Vs[sc0][drow][0];
#pragma unroll
      for (int r = 0; r < 4; ++r) GLDS16(gv + r * 16, lv + r * 2048);
    }
    __syncthreads();

    // ---- scores: S = Q @ K^T ----
    f32x4 sacc[2][4];
#pragma unroll
    for (int mi = 0; mi < 2; ++mi)
#pragma unroll
      for (int j = 0; j < 4; ++j) sacc[mi][j] = (f32x4){0.f, 0.f, 0.f, 0.f};
#pragma unroll
    for (int ks = 0; ks < 4; ++ks) {
      bf16x8 bk[4];
#pragma unroll
      for (int j = 0; j < 4; ++j)
        bk[j] = *(const bf16x8*)&Ks[ks * 4 + quad][j * 16 + col][0];
#pragma unroll
      for (int mi = 0; mi < 2; ++mi)
#pragma unroll
        for (int j = 0; j < 4; ++j)
          sacc[mi][j] = __builtin_amdgcn_mfma_f32_16x16x32_bf16(
              qf[mi][ks], bk[j], sacc[mi][j], 0, 0, 0);
    }

    // ---- online softmax (row = wave*32 + mi*16 + quad*4 + r) ----
#pragma unroll
    for (int mi = 0; mi < 2; ++mi) {
#pragma unroll
      for (int r = 0; r < 4; ++r) {
        float mx = sacc[mi][0][r];
#pragma unroll
        for (int j = 1; j < 4; ++j) mx = fmaxf(mx, sacc[mi][j][r]);
        mx = fmaxf(mx, __shfl_xor(mx, 1));
        mx = fmaxf(mx, __shfl_xor(mx, 2));
        mx = fmaxf(mx, __shfl_xor(mx, 4));
        mx = fmaxf(mx, __shfl_xor(mx, 8));
        mx *= scale;
        float mold = mrow[mi][r];
        float mnew = fmaxf(mold, mx);
        float alpha = exp2f((mold - mnew) * l2e);
        mrow[mi][r] = mnew;
        float rsum = 0.f;
#pragma unroll
        for (int j = 0; j < 4; ++j) {
          float pv = exp2f((sacc[mi][j][r] * scale - mnew) * l2e);
          sacc[mi][j][r] = pv;
          rsum += pv;
        }
        rsum += __shfl_xor(rsum, 1);
        rsum += __shfl_xor(rsum, 2);
        rsum += __shfl_xor(rsum, 4);
        rsum += __shfl_xor(rsum, 8);
        lrow[mi][r] = lrow[mi][r] * alpha + rsum;
#pragma unroll
        for (int d = 0; d < 8; ++d) oacc[mi][d][r] *= alpha;
        int prow = wave * 32 + mi * 16 + quad * 4 + r;
#pragma unroll
        for (int j = 0; j < 4; ++j) {
          int sc = (j * 16 + col) >> 3;
          Ps[sc][prow][col & 7] = f2b(sacc[mi][j][r]);
        }
      }
    }
    // (P rows wave-private; same-wave DS ordering suffices.)

    // ---- O += P @ V ----
#pragma unroll
    for (int ks = 0; ks < 2; ++ks) {
      bf16x8 ap[2];
#pragma unroll
      for (int mi = 0; mi < 2; ++mi)
        ap[mi] = *(const bf16x8*)&Ps[ks * 4 + quad][wave * 32 + mi * 16 + col][0];
#pragma unroll
      for (int di = 0; di < 8; ++di) {
        bf16x8 bv = *(const bf16x8*)&Vs[ks * 4 + quad][di * 16 + col][0];
#pragma unroll
        for (int mi = 0; mi < 2; ++mi)
          oacc[mi][di] = __builtin_amdgcn_mfma_f32_16x16x32_bf16(
              ap[mi], bv, oacc[mi][di], 0, 0, 0);
      }
    }
  }

  // ---- epilogue: ctx[b*T + t][h*128 + d] = O / l ----
#pragma unroll
  for (int mi = 0; mi < 2; ++mi) {
#pragma unroll
    for (int r = 0; r < 4; ++r) {
      float inv = 1.0f / lrow[mi][r];
      int row = qt * 128 + wave * 32 + mi * 16 + quad * 4 + r;
#pragma unroll
      for (int di = 0; di < 8; ++di)
        ctx[(size_t)(b * T + row) * 4096 + h * 128 + di * 16 + col] =
            f2b(oacc[mi][di][r] * inv);
    }
  }
}

// ---------------------------------------------------------------------------
// launch
// ---------------------------------------------------------------------------
extern "C" void kernel_launch(void* const* d_in, const int* in_sizes, int n_in,
                              void* d_out, int out_size, void* d_ws,
                              size_t ws_size, hipStream_t stream) {
  const float* x  = (const float*)d_in[0];
  const float* wq = (const float*)d_in[1];
  const float* wk = (const float*)d_in[2];
  const float* wv = (const float*)d_in[3];
  const float* wo = (const float*)d_in[4];
  const float* fc = (const float*)d_in[5];
  const float* fs = (const float*)d_in[6];
  float* out = (float*)d_out;

  char* ws = (char*)d_ws;
  unsigned short* xb  = (unsigned short*)(ws);
  unsigned short* wb  = (unsigned short*)(ws + 33554432);
  unsigned short* qkv = (unsigned short*)(ws + 33554432 + 50331648);
  unsigned short* vtp = (unsigned short*)(ws + 33554432 + 50331648 + 50331648);

  cast_f32_bf16<<<16384, 256, 0, stream>>>(x, xb, 4194304);
  cast_f32_bf16<<<16384, 256, 0, stream>>>(wq, wb, 4194304);
  cast_f32_bf16<<<4096, 256, 0, stream>>>(wk, wb + 16777216, 1048576);
  cast_f32_bf16<<<4096, 256, 0, stream>>>(wv, wb + 20971520, 1048576);

  dim3 g1(48, 32);
  gemm_bt<unsigned short><<<g1, 256, 0, stream>>>(xb, wb, qkv, 4096, 6144, 4096);

  cast_f32_bf16<<<16384, 256, 0, stream>>>(wo, wb, 4194304);  // reuse region B

  rope_qk<<<40960, 256, 0, stream>>>(qkv, fc, fs);

  dim3 g2(32, 2, 16);
  transpose_v<<<g2, 256, 0, stream>>>(qkv, vtp);

  dim3 g3(16, 32, 2);
  attn<<<g3, 256, 0, stream>>>(qkv, vtp, xb);  // ctx -> region A

  dim3 g4(32, 32);
  gemm_bt<float><<<g4, 256, 0, stream>>>(xb, wb, out, 4096, 4096, 4096);
}

// Round 4
// 813.185 us; speedup vs baseline: 1.6117x; 1.1433x over previous
//
#include <hip/hip_runtime.h>
#include <hip/hip_bf16.h>
#include <cstdint>

// ---------------------------------------------------------------------------
// Attention block, bf16 MFMA pipeline:
//   cast -> fused QKV GEMM -> RoPE -> V transpose -> flash attention -> O GEMM
// Shapes: B=2 T=2048 DIM=4096 H=32 KVH=8 D=128, no mask, start_pos=0.
// KV mapping: jnp.tile -> Q-head h attends KV-head (h % 8).
// R4: attn restructured — scores computed TRANSPOSED (S^T = K·Q^T) so each
// lane owns whole Q-rows: in-lane softmax + 2 shuffles (was 64), packed b64
// P-writes (was 32 scalar u16 w/ conflicts), PV as O^T = V^T·P. K/V staging
// coalesced+swizzled like the R3 GEMM fix.
// ---------------------------------------------------------------------------

typedef short bf16x8 __attribute__((ext_vector_type(8)));   // 8 bf16 = 4 VGPRs
typedef float f32x4  __attribute__((ext_vector_type(4)));

__device__ __forceinline__ float b2f(unsigned short h) {
  union { uint32_t u; float f; } v; v.u = ((uint32_t)h) << 16; return v.f;
}
__device__ __forceinline__ unsigned short f2b(float f) {
  union { float f; uint32_t u; } v; v.f = f;
  uint32_t r = (v.u + 0x7FFFu + ((v.u >> 16) & 1u)) >> 16;
  return (unsigned short)r;
}

#define GLDS16(gp, lp)                                                        \
  __builtin_amdgcn_global_load_lds(                                           \
      (const __attribute__((address_space(1))) unsigned int*)(gp),            \
      (__attribute__((address_space(3))) unsigned int*)(lp), 16, 0, 0)

// ---------------------------------------------------------------------------
// fp32 -> bf16 cast, 4 elements/thread
// ---------------------------------------------------------------------------
__global__ __launch_bounds__(256) void cast_f32_bf16(
    const float* __restrict__ in, unsigned short* __restrict__ out, int n4) {
  int i = blockIdx.x * 256 + threadIdx.x;
  if (i < n4) {
    float4 v = ((const float4*)in)[i];
    ushort4 o;
    o.x = f2b(v.x); o.y = f2b(v.y); o.z = f2b(v.z); o.w = f2b(v.w);
    ((ushort4*)out)[i] = o;
  }
}

// ---------------------------------------------------------------------------
// GEMM  C[m,n] = sum_k A[m,k]*B[n,k]  (unchanged from R3 — 930us config)
// ---------------------------------------------------------------------------
__device__ __forceinline__ void stout(float* p, float v) { *p = v; }
__device__ __forceinline__ void stout(unsigned short* p, float v) { *p = f2b(v); }

template <typename OUT>
__global__ __launch_bounds__(256, 2) void gemm_bt(
    const unsigned short* __restrict__ A, const unsigned short* __restrict__ B,
    OUT* __restrict__ C, int M, int N, int K) {
  __shared__ __align__(16) unsigned short As[128][64];  // 16 KB
  __shared__ __align__(16) unsigned short Bs[128][64];  // 16 KB

  const int tid  = threadIdx.x;
  const int lane = tid & 63;
  const int wave = tid >> 6;
  const int col  = lane & 15;
  const int quad = lane >> 4;
  const int bm = blockIdx.y * 128;
  const int bn = blockIdx.x * 128;
  const int wm = (wave & 1) * 64;
  const int wn = (wave >> 1) * 64;

  f32x4 acc[4][4];
#pragma unroll
  for (int i = 0; i < 4; ++i)
#pragma unroll
    for (int j = 0; j < 4; ++j) acc[i][j] = (f32x4){0.f, 0.f, 0.f, 0.f};

  const int srow0  = tid >> 3;                    // 0..31
  const int gchunk = (tid & 7) ^ ((tid >> 3) & 7);
  const unsigned short* Ag = A + (size_t)(bm + srow0) * K + gchunk * 8;
  const unsigned short* Bg = B + (size_t)(bn + srow0) * K + gchunk * 8;
  unsigned short* Al = &As[0][0] + tid * 8;
  unsigned short* Bl = &Bs[0][0] + tid * 8;

  for (int k0 = 0; k0 < K; k0 += 64) {
    __syncthreads();
#pragma unroll
    for (int r = 0; r < 4; ++r) {
      GLDS16(Ag + k0 + (size_t)r * 32 * K, Al + r * 2048);
      GLDS16(Bg + k0 + (size_t)r * 32 * K, Bl + r * 2048);
    }
    __syncthreads();
#pragma unroll
    for (int ks = 0; ks < 2; ++ks) {
      bf16x8 a[4], b[4];
      const int slot = ((ks * 4 + quad) ^ (col & 7)) * 8;
#pragma unroll
      for (int i = 0; i < 4; ++i)
        a[i] = *(const bf16x8*)&As[wm + i * 16 + col][slot];
#pragma unroll
      for (int j = 0; j < 4; ++j)
        b[j] = *(const bf16x8*)&Bs[wn + j * 16 + col][slot];
#pragma unroll
      for (int i = 0; i < 4; ++i)
#pragma unroll
        for (int j = 0; j < 4; ++j)
          acc[i][j] = __builtin_amdgcn_mfma_f32_16x16x32_bf16(a[i], b[j],
                                                              acc[i][j], 0, 0, 0);
    }
  }

#pragma unroll
  for (int i = 0; i < 4; ++i) {
    int row = bm + wm + i * 16 + quad * 4;
#pragma unroll
    for (int j = 0; j < 4; ++j) {
      int cc = bn + wn + j * 16 + col;
#pragma unroll
      for (int r2 = 0; r2 < 4; ++r2)
        stout(C + (size_t)(row + r2) * N + cc, acc[i][j][r2]);
    }
  }
}

// ---------------------------------------------------------------------------
// RoPE in-place on qkv (4096 rows x 6144 cols): heads 0..31 = q, 32..39 = k.
// ---------------------------------------------------------------------------
__global__ __launch_bounds__(256) void rope_qk(
    unsigned short* __restrict__ qkv, const float* __restrict__ cosT,
    const float* __restrict__ sinT) {
  int idx = blockIdx.x * 256 + threadIdx.x;  // < 4096*2560
  int m = idx / 2560;
  int p = idx - m * 2560;
  int head = p >> 6, i = p & 63;
  int t = m & 2047;
  unsigned short* ptr = qkv + (size_t)m * 6144 + head * 128 + i * 2;
  ushort2 xy = *(const ushort2*)ptr;
  float x = b2f(xy.x), y = b2f(xy.y);
  float c = cosT[t * 64 + i], s = sinT[t * 64 + i];
  ushort2 o;
  o.x = f2b(x * c - y * s);
  o.y = f2b(x * s + y * c);
  *(ushort2*)ptr = o;
}

// ---------------------------------------------------------------------------
// V transpose: vt[(b*8+kvh)*128 + d][s] = qkv[b*2048+s][5120 + kvh*128 + d]
// ---------------------------------------------------------------------------
__global__ __launch_bounds__(256) void transpose_v(
    const unsigned short* __restrict__ qkv, unsigned short* __restrict__ vt) {
  __shared__ unsigned short tile[64][72];
  int b = blockIdx.z >> 3, kvh = blockIdx.z & 7;
  int s0 = blockIdx.x * 64, d0 = blockIdx.y * 64;
  int tc = threadIdx.x & 63, tr = threadIdx.x >> 6;  // tr 0..3
#pragma unroll
  for (int r = 0; r < 16; ++r) {
    int row = r * 4 + tr;  // s within tile
    tile[row][tc] =
        qkv[(size_t)(b * 2048 + s0 + row) * 6144 + 5120 + kvh * 128 + d0 + tc];
  }
  __syncthreads();
#pragma unroll
  for (int r = 0; r < 16; ++r) {
    int drow = r * 4 + tr;  // d within tile
    vt[(size_t)((b * 8 + kvh) * 128 + d0 + drow) * 2048 + s0 + tc] =
        tile[tc][drow];
  }
}

// ---------------------------------------------------------------------------
// Flash attention, transposed-score formulation.
// grid (qt=16, h=32, b=2), 256 threads (4 waves), S-tile 64.
// S^T = K·Q^T  : lane owns Q-row q = wave*32+mi*16+(lane&15); 16 scores
//                in-lane per tile -> in-lane max/sum + shfl_xor(16,32).
// P packed in-lane -> ds_write_b64 into Ps[q][72-pitch] (conflict-free).
// O^T = V^T·P  : A-frag from Vs (V^T tile), B-frag = ds_read_b128 from Ps.
// LDS: Ks [64][128] + Vs [128][64] (both XOR-swizzled chunk slots, staged
// coalesced: 8/16 lanes per global row segment), Ps [128][72]. 50 KB.
// ---------------------------------------------------------------------------
__global__ __launch_bounds__(256, 2) void attn(
    const unsigned short* __restrict__ qkv, const unsigned short* __restrict__ vt,
    unsigned short* __restrict__ ctx) {
  constexpr int T = 2048, LD = 6144;
  const int qt = blockIdx.x, h = blockIdx.y, b = blockIdx.z;
  const int kvh = h & 7;  // jnp.tile semantics
  const int tid = threadIdx.x, lane = tid & 63, wave = tid >> 6;
  const int col = lane & 15, quad = lane >> 4;

  __shared__ __align__(1024) char smem[51200];
  auto Qs = (unsigned short(*)[128][8])smem;           // [16][128][8] phase 0 (32KB)
  auto Ks = (unsigned short(*)[128])smem;              // [64][128]  16KB
  auto Vs = (unsigned short(*)[64])(smem + 16384);     // [128][64]  16KB
  auto Ps = (unsigned short(*)[72])(smem + 32768);     // [128][72]  18KB

  // ---- stage Q tile (128 x 128) ----
  {
    const int row = tid & 127, kc0 = tid >> 7;
    const unsigned short* g =
        qkv + (size_t)(b * T + qt * 128 + row) * LD + h * 128 + kc0 * 8;
    unsigned short* l = &Qs[kc0][row][0];
#pragma unroll
    for (int r = 0; r < 8; ++r) GLDS16(g + r * 16, l + r * 2048);
  }
  __syncthreads();

  bf16x8 qf[2][4];
#pragma unroll
  for (int mi = 0; mi < 2; ++mi)
#pragma unroll
    for (int ks = 0; ks < 4; ++ks)
      qf[mi][ks] = *(const bf16x8*)&Qs[ks * 4 + quad][wave * 32 + mi * 16 + col][0];

  float mrow[2], lrow[2];
  f32x4 oacc[2][8];  // O^T: lane q = wave*32+mi*16+col, d = di*16+quad*4+r
#pragma unroll
  for (int mi = 0; mi < 2; ++mi) { mrow[mi] = -1e30f; lrow[mi] = 0.f; }
#pragma unroll
  for (int mi = 0; mi < 2; ++mi)
#pragma unroll
    for (int d = 0; d < 8; ++d) oacc[mi][d] = (f32x4){0.f, 0.f, 0.f, 0.f};

  const float scale = 0.08838834764831845f;  // 1/sqrt(128)
  const float l2e = 1.4426950408889634f;

  // staging constants (coalesced + XOR swizzle, r-invariant)
  const int krow0 = tid >> 4;                       // 0..15  (K: 16 lanes/row)
  const int kgch  = (tid & 15) ^ ((tid >> 4) & 15); // K chunk 0..15
  const int vrow0 = tid >> 3;                       // 0..31  (V: 8 lanes/row)
  const int vgch  = (tid & 7) ^ ((tid >> 3) & 7);   // V chunk 0..7
  unsigned short* Klin = &Ks[0][0] + tid * 8;
  unsigned short* Vlin = &Vs[0][0] + tid * 8;

  for (int s0 = 0; s0 < T; s0 += 64) {
    __syncthreads();
    // ---- stage K tile [64 s][128 d]: 4 GLDS, 16 full lines each ----
    {
      const unsigned short* g =
          qkv + (size_t)(b * T + s0 + krow0) * LD + 4096 + kvh * 128 + kgch * 8;
#pragma unroll
      for (int r = 0; r < 4; ++r)
        GLDS16(g + (size_t)r * 16 * LD, Klin + r * 2048);
      // ---- stage V^T tile [128 d][64 s]: 4 GLDS ----
      const unsigned short* gv =
          vt + (size_t)((b * 8 + kvh) * 128 + vrow0) * T + s0 + vgch * 8;
#pragma unroll
      for (int r = 0; r < 4; ++r)
        GLDS16(gv + (size_t)r * 32 * T, Vlin + r * 2048);
    }
    __syncthreads();

    // ---- scores transposed: S^T = K·Q^T (A=K-frag, B=Q-frag) ----
    // sacc[mi][j][r] = S[q = wave*32+mi*16+col][s = 16j + quad*4 + r]
    f32x4 sacc[2][4];
#pragma unroll
    for (int mi = 0; mi < 2; ++mi)
#pragma unroll
      for (int j = 0; j < 4; ++j) sacc[mi][j] = (f32x4){0.f, 0.f, 0.f, 0.f};
#pragma unroll
    for (int ks = 0; ks < 4; ++ks) {
      bf16x8 ak[4];
#pragma unroll
      for (int j = 0; j < 4; ++j)
        ak[j] = *(const bf16x8*)&Ks[j * 16 + col][((ks * 4 + quad) ^ col) * 8];
#pragma unroll
      for (int mi = 0; mi < 2; ++mi)
#pragma unroll
        for (int j = 0; j < 4; ++j)
          sacc[mi][j] = __builtin_amdgcn_mfma_f32_16x16x32_bf16(
              ak[j], qf[mi][ks], sacc[mi][j], 0, 0, 0);
    }

    // ---- online softmax: lane owns rows q(mi) entirely (16 vals + 2 shfl) ----
#pragma unroll
    for (int mi = 0; mi < 2; ++mi) {
      const int q = wave * 32 + mi * 16 + col;
      float mx = sacc[mi][0][0];
#pragma unroll
      for (int j = 0; j < 4; ++j)
#pragma unroll
        for (int r = 0; r < 4; ++r) mx = fmaxf(mx, sacc[mi][j][r]);
      mx = fmaxf(mx, __shfl_xor(mx, 16));
      mx = fmaxf(mx, __shfl_xor(mx, 32));
      mx *= scale;
      float mold = mrow[mi];
      float mnew = fmaxf(mold, mx);
      float alpha = exp2f((mold - mnew) * l2e);
      mrow[mi] = mnew;
      float rsum = 0.f;
#pragma unroll
      for (int j = 0; j < 4; ++j) {
        ushort4 pk;
#pragma unroll
        for (int r = 0; r < 4; ++r) {
          float pv = exp2f((sacc[mi][j][r] * scale - mnew) * l2e);
          rsum += pv;
          ((unsigned short*)&pk)[r] = f2b(pv);
        }
        *(ushort4*)&Ps[q][j * 16 + quad * 4] = pk;  // ds_write_b64
      }
      rsum += __shfl_xor(rsum, 16);
      rsum += __shfl_xor(rsum, 32);
      lrow[mi] = lrow[mi] * alpha + rsum;
#pragma unroll
      for (int di = 0; di < 8; ++di) {
#pragma unroll
        for (int r = 0; r < 4; ++r) oacc[mi][di][r] *= alpha;
      }
    }
    // (Ps rows are wave-private; same-wave DS ops are in-order.)

    // ---- O^T += V^T · P  (A=V^T-frag from Vs, B=P-frag from Ps) ----
#pragma unroll
    for (int mi = 0; mi < 2; ++mi) {
      const int q = wave * 32 + mi * 16 + col;
      bf16x8 bp[2];
      bp[0] = *(const bf16x8*)&Ps[q][quad * 8];
      bp[1] = *(const bf16x8*)&Ps[q][32 + quad * 8];
#pragma unroll
      for (int ks = 0; ks < 2; ++ks) {
#pragma unroll
        for (int di = 0; di < 8; ++di) {
          bf16x8 va = *(const bf16x8*)
              &Vs[di * 16 + col][(((ks * 4 + quad) ^ (col & 7))) * 8];
          oacc[mi][di] = __builtin_amdgcn_mfma_f32_16x16x32_bf16(
              va, bp[ks], oacc[mi][di], 0, 0, 0);
        }
      }
    }
  }

  // ---- epilogue: ctx[b*T + q][h*128 + d] = O^T / l (transposed scatter) ----
#pragma unroll
  for (int mi = 0; mi < 2; ++mi) {
    float inv = 1.0f / lrow[mi];
    int row = qt * 128 + wave * 32 + mi * 16 + col;
    unsigned short* cp = ctx + (size_t)(b * T + row) * 4096 + h * 128;
#pragma unroll
    for (int di = 0; di < 8; ++di)
#pragma unroll
      for (int r = 0; r < 4; ++r)
        cp[di * 16 + quad * 4 + r] = f2b(oacc[mi][di][r] * inv);
  }
}

// ---------------------------------------------------------------------------
// launch
// ---------------------------------------------------------------------------
extern "C" void kernel_launch(void* const* d_in, const int* in_sizes, int n_in,
                              void* d_out, int out_size, void* d_ws,
                              size_t ws_size, hipStream_t stream) {
  const float* x  = (const float*)d_in[0];
  const float* wq = (const float*)d_in[1];
  const float* wk = (const float*)d_in[2];
  const float* wv = (const float*)d_in[3];
  const float* wo = (const float*)d_in[4];
  const float* fc = (const float*)d_in[5];
  const float* fs = (const float*)d_in[6];
  float* out = (float*)d_out;

  char* ws = (char*)d_ws;
  unsigned short* xb  = (unsigned short*)(ws);
  unsigned short* wb  = (unsigned short*)(ws + 33554432);
  unsigned short* qkv = (unsigned short*)(ws + 33554432 + 50331648);
  unsigned short* vtp = (unsigned short*)(ws + 33554432 + 50331648 + 50331648);

  cast_f32_bf16<<<16384, 256, 0, stream>>>(x, xb, 4194304);
  cast_f32_bf16<<<16384, 256, 0, stream>>>(wq, wb, 4194304);
  cast_f32_bf16<<<4096, 256, 0, stream>>>(wk, wb + 16777216, 1048576);
  cast_f32_bf16<<<4096, 256, 0, stream>>>(wv, wb + 20971520, 1048576);

  dim3 g1(48, 32);
  gemm_bt<unsigned short><<<g1, 256, 0, stream>>>(xb, wb, qkv, 4096, 6144, 4096);

  cast_f32_bf16<<<16384, 256, 0, stream>>>(wo, wb, 4194304);  // reuse region B

  rope_qk<<<40960, 256, 0, stream>>>(qkv, fc, fs);

  dim3 g2(32, 2, 16);
  transpose_v<<<g2, 256, 0, stream>>>(qkv, vtp);

  dim3 g3(16, 32, 2);
  attn<<<g3, 256, 0, stream>>>(qkv, vtp, xb);  // ctx -> region A

  dim3 g4(32, 32);
  gemm_bt<float><<<g4, 256, 0, stream>>>(xb, wb, out, 4096, 4096, 4096);
}